// Round 7
// baseline (15963.933 us; speedup 1.0000x reference)
//
#include <hip/hip_runtime.h>

#define NN 16384   // n_nodes
#define DD 64      // feature dim
#define SPLIT 2              // K-halves
#define KH (NN / SPLIT)      // 8192 K per block

typedef _Float16 f16x8 __attribute__((ext_vector_type(8)));
typedef short    s16x8 __attribute__((ext_vector_type(8)));
typedef float    f32x4 __attribute__((ext_vector_type(4)));
typedef int      i32x4 __attribute__((ext_vector_type(4)));
typedef unsigned u32;

// ---------------------------------------------------------------------------
// prep_x: convert x (fp32 [NN][64]) into f16 in exact MFMA B-fragment order:
//   xs[((T*4 + c)*64 + l)*8 + j] = x[32*T + (l>>4)*8 + j][c*16 + (l&15)]
// Coalesced via an LDS transpose of each 32x64 tile.  (proven R2-R6)
// ---------------------------------------------------------------------------
__global__ __launch_bounds__(256) void prep_x(const float* __restrict__ x,
                                              _Float16* __restrict__ ws) {
    __shared__ float sx[32][65];
    const int tid = threadIdx.x;
    const int t   = blockIdx.x;    // 0..511 ; x rows 32t .. 32t+31 (= K dim)
    {
        int r  = tid >> 3;
        int c8 = (tid & 7) * 8;
        const float* src = x + ((size_t)t * 32 + r) * DD + c8;
        f32x4 a = *(const f32x4*)src;
        f32x4 b = *(const f32x4*)(src + 4);
#pragma unroll
        for (int j = 0; j < 4; ++j) { sx[r][c8 + j] = a[j]; sx[r][c8 + 4 + j] = b[j]; }
    }
    __syncthreads();
    const int l = tid & 63;
    const int c = tid >> 6;
    const int q = l >> 4;
    const int m = l & 15;
    f16x8 v;
#pragma unroll
    for (int j = 0; j < 8; ++j)
        v[j] = (_Float16)sx[q * 8 + j][c * 16 + m];
    *(f16x8*)(ws + (((size_t)t * 256 + c * 64 + l) * 8)) = v;
}

// ---------------------------------------------------------------------------
// Two-phase GEMM.  Block (rb,kh): rows rb*64..+63, K range [kh*8192,+8192).
//
// PHASE 1 (the fix): each wave streams its 16 adj rows LINEARLY -- per
// (row, 2048-col pass) the wave reads one contiguous 8 KiB region (lane l
// covers cols l*32..+31 via 8x dwordx4, cached so the 4 loads per 64-B line
// all hit L1).  Long per-row linear streams = the D2D/fill access pattern
// that is proven to run ~6 TB/s, unlike every prior 16-row-interleaved
// tiling which plateaued at ~1.6 TB/s.  Each lane bit-packs its 32 ints into
// one dword -> LDS bit-tile [64 rows][256 dwords] (64 KiB), XOR-swizzled
// (dword index ^ 4*(row&7)) so phase-2's 16-row column read is 2-way (free).
//
// PHASE 2: one barrier, then 256 k-steps of MFMA.  A-frag: ds_read_b32 of
// the row's bit-dword + shift(8q) + 8 bit-tests (bit b of dword t is
// adj[row][kh*8192 + 32t + b]; frag needs bits 8q+j -- exact match).
// B-frag: double-buffered global loads from L2/L1-hot xs; no adj loads are
// outstanding in phase 2, so B's vmcnt waits drain nothing that matters.
// ---------------------------------------------------------------------------
__global__ __launch_bounds__(256, 2) void graphpool_gemm(const int* __restrict__ adj,
                                                         const _Float16* __restrict__ xs,
                                                         float* __restrict__ part) {
    __shared__ u32 sbits[64][256];   // 64 KiB bit-tile

    const int tid = threadIdx.x;
    const int w   = tid >> 6;
    const int l   = tid & 63;
    const int q   = l >> 4;
    const int m   = l & 15;

    const int rb    = blockIdx.x >> 1;   // row-block 0..255
    const int kh    = blockIdx.x & 1;    // K-half 0..1
    const int row16 = rb * 64 + w * 16;

    // ---- phase 1: pack this wave's 16 rows x 8192 cols into LDS bits ----
    // unit u: row rr=u>>2, pass=u&3; lane packs dword g = (u&3)*64 + l.
    i32x4 areg[2][8];
    auto loadU = [&](int u, int buf) {
        const int rr = u >> 2, pass = u & 3;
        const i32x4* p = (const i32x4*)(adj + (size_t)(row16 + rr) * NN
                                        + (size_t)kh * KH + pass * 2048 + l * 32);
#pragma unroll
        for (int j = 0; j < 8; ++j) areg[buf][j] = p[j];   // cached: line reuse
    };

    loadU(0, 0);
    for (int u = 0; u < 64; ++u) {
        const int buf = u & 1;
        if (u + 1 < 64) loadU(u + 1, buf ^ 1);   // counted vmcnt, no drain
        u32 b = 0;
#pragma unroll
        for (int j = 0; j < 8; ++j) {
            i32x4 v = areg[buf][j];
            b |= (u32)(v.x != 0) << (4 * j);
            b |= (u32)(v.y != 0) << (4 * j + 1);
            b |= (u32)(v.z != 0) << (4 * j + 2);
            b |= (u32)(v.w != 0) << (4 * j + 3);
        }
        const int rr = u >> 2;
        const u32 cR = 4u * (u32)(rr & 7);               // (w*16+rr)&7 == rr&7
        sbits[w * 16 + rr][((u32)((u & 3) * 64 + l)) ^ cR] = b;
    }
    __syncthreads();

    // ---- phase 2: MFMA over K=8192 ----
    const u32  cR   = 4u * (u32)(m & 7);
    const u32* srow = sbits[w * 16 + m];
    const f16x8* xv = (const f16x8*)xs + l;   // + (T*4+c)*64

    f32x4 acc[4];
#pragma unroll
    for (int c = 0; c < 4; ++c) acc[c] = (f32x4){0.f, 0.f, 0.f, 0.f};

    f16x8 breg[2][4];
    u32   bitreg[2];
    auto loadB = [&](int t, int buf) {        // t = local kstep 0..255
        const size_t T = (size_t)kh * 256 + t;
#pragma unroll
        for (int c = 0; c < 4; ++c) breg[buf][c] = xv[(T * 4 + c) * 64];
    };

    bitreg[0] = srow[0u ^ cR];
    loadB(0, 0);

    for (int t = 0; t < 256; ++t) {
        const int buf = t & 1;
        if (t + 1 < 256) {
            bitreg[buf ^ 1] = srow[((u32)(t + 1)) ^ cR];
            loadB(t + 1, buf ^ 1);
        }
        const u32 d = bitreg[buf] >> (8 * q);   // bits 8q+j -> j
        s16x8 ai;
#pragma unroll
        for (int j = 0; j < 8; ++j)
            ai[j] = ((d >> j) & 1u) ? (short)0x3C00 : (short)0;
        f16x8 af = __builtin_bit_cast(f16x8, ai);
#pragma unroll
        for (int c = 0; c < 4; ++c)
            acc[c] = __builtin_amdgcn_mfma_f32_16x16x32_f16(af, breg[buf][c], acc[c], 0, 0, 0);
    }

    // partial C write: col = c*16+m, row = q*4+r  (8 MiB total, L3-hot)
    float* po = part + (size_t)kh * NN * DD;
#pragma unroll
    for (int c = 0; c < 4; ++c) {
#pragma unroll
        for (int r = 0; r < 4; ++r) {
            size_t off = (size_t)(row16 + q * 4 + r) * DD + c * 16 + m;
            po[off] = acc[c][r];
        }
    }
}

// ---------------------------------------------------------------------------
// Final reduce: out = part[0] + part[1] + x (self term). ~16 MiB, ~4 us.
// ---------------------------------------------------------------------------
__global__ __launch_bounds__(256) void reduce_add(const float* __restrict__ part,
                                                  const float* __restrict__ x,
                                                  float* __restrict__ out) {
    size_t i = (size_t)blockIdx.x * 256 + threadIdx.x;   // f32x4 index, 262144 total
    f32x4 v = ((const f32x4*)x)[i];
    v += ((const f32x4*)part)[i];
    v += ((const f32x4*)(part + (size_t)NN * DD))[i];
    ((f32x4*)out)[i] = v;
}

// ---------------------------------------------------------------------------
// Safety-net fallback if ws is too small (needs 2 MiB xs + 8 MiB partials).
// ---------------------------------------------------------------------------
__global__ void graphpool_fallback(const int* __restrict__ adj,
                                   const float* __restrict__ x,
                                   float* __restrict__ out) {
    int i = blockIdx.x;
    int d = threadIdx.x;   // 64 threads
    float acc = x[(size_t)i * DD + d];
    const int* row = adj + (size_t)i * NN;
    for (int j = 0; j < NN; ++j)
        if (row[j]) acc += x[(size_t)j * DD + d];
    out[(size_t)i * DD + d] = acc;
}

extern "C" void kernel_launch(void* const* d_in, const int* in_sizes, int n_in,
                              void* d_out, int out_size, void* d_ws, size_t ws_size,
                              hipStream_t stream) {
    const float* x   = (const float*)d_in[0];
    const int*   adj = (const int*)d_in[1];
    float*       out = (float*)d_out;

    const size_t xs_bytes   = (size_t)NN * DD * sizeof(_Float16);        // 2 MiB
    const size_t part_bytes = (size_t)SPLIT * NN * DD * sizeof(float);   // 8 MiB
    if (ws_size >= xs_bytes + part_bytes) {
        _Float16* xs   = (_Float16*)d_ws;
        float*    part = (float*)((char*)d_ws + xs_bytes);
        prep_x<<<512, 256, 0, stream>>>(x, xs);
        graphpool_gemm<<<256 * SPLIT, 256, 0, stream>>>(adj, xs, part);
        reduce_add<<<1024, 256, 0, stream>>>(part, x, out);
    } else {
        graphpool_fallback<<<NN, 64, 0, stream>>>(adj, x, out);
    }
}

// Round 8
// 1568.914 us; speedup vs baseline: 10.1752x; 10.1752x over previous
//
#include <hip/hip_runtime.h>

#define NN 16384   // n_nodes
#define DD 64      // feature dim

typedef _Float16 f16x8 __attribute__((ext_vector_type(8)));
typedef short    s16x8 __attribute__((ext_vector_type(8)));
typedef float    f32x4 __attribute__((ext_vector_type(4)));
typedef int      i32x4 __attribute__((ext_vector_type(4)));
typedef unsigned u32;
typedef unsigned long long u64;

// ---------------------------------------------------------------------------
// pack_adj: bit-pack adj (1 GiB of 0/1 int32) -> pk (32 MiB), at HBM speed.
// THE access pattern (m13 copy pattern): each wave owns a contiguous 256 KiB
// slice; per iteration it reads 2 KiB as TWO lane-contiguous dwordx4 loads
// (instr i, lane l -> ints [seg*512 + i*256 + 4l, +4)), double-buffered.
// Packing: 8 x __ballot (one per vector element) -> 8 x u64 covering the
// 512 cols; a 15-op cndmask tree gives lane n (n<16) output dword d=n:
//   d = i*8 + e*2 + h  (i=c'>>8, e=c'&3, h=(c'>>7)&1), bit b=(c'>>2)&31,
//   i.e. pk dword d bit b <-> col  i*256 + h*128 + 4b + e   of the segment.
// Segment = (row, 512-col block): seg = row*32 + blk; pk dword = seg*16 + d.
// ---------------------------------------------------------------------------
__global__ __launch_bounds__(256) void pack_adj(const int* __restrict__ adj,
                                                u32* __restrict__ pk) {
    const int tid = threadIdx.x;
    const int w   = tid >> 6;
    const int l   = tid & 63;
    const int g   = blockIdx.x * 4 + w;    // global wave 0..4095

    i32x4 v[2][2];                         // [buf][i] : 16 VGPRs
    auto segLoad = [&](int it, int buf) {
        const size_t seg = (size_t)g * 128 + it;
        const i32x4* p = (const i32x4*)(adj + seg * 512) + l;
        v[buf][0] = p[0];                  // i=0: cols 4l..4l+3
        v[buf][1] = p[64];                 // i=1: cols 256+4l..+3
    };

    segLoad(0, 0);
    for (int it = 0; it < 128; ++it) {
        const int buf = it & 1;
        if (it + 1 < 128) segLoad(it + 1, buf ^ 1);

        const u64 b00 = __ballot(v[buf][0].x != 0);   // i=0,e=0
        const u64 b01 = __ballot(v[buf][0].y != 0);
        const u64 b02 = __ballot(v[buf][0].z != 0);
        const u64 b03 = __ballot(v[buf][0].w != 0);
        const u64 b10 = __ballot(v[buf][1].x != 0);   // i=1
        const u64 b11 = __ballot(v[buf][1].y != 0);
        const u64 b12 = __ballot(v[buf][1].z != 0);
        const u64 b13 = __ballot(v[buf][1].w != 0);

        auto half = [&](u64 b) { return (l & 1) ? (u32)(b >> 32) : (u32)b; };
        const u32 e0 = half(b00), e1 = half(b01), e2 = half(b02), e3 = half(b03);
        const u32 f0 = half(b10), f1 = half(b11), f2 = half(b12), f3 = half(b13);
        const u32 x01 = ((l >> 1) & 1) ? e1 : e0;
        const u32 x23 = ((l >> 1) & 1) ? e3 : e2;
        const u32 xe  = ((l >> 2) & 1) ? x23 : x01;
        const u32 y01 = ((l >> 1) & 1) ? f1 : f0;
        const u32 y23 = ((l >> 1) & 1) ? f3 : f2;
        const u32 yf  = ((l >> 2) & 1) ? y23 : y01;
        const u32 val = ((l >> 3) & 1) ? yf : xe;

        if (l < 16) {
            const size_t seg = (size_t)g * 128 + it;
            pk[seg * 16 + l] = val;
        }
    }
}

// ---------------------------------------------------------------------------
// prep_x: convert x (fp32 [NN][64]) into f16 in exact MFMA B-fragment order:
//   xs[((T*4 + c)*64 + l)*8 + j] = x[32*T + (l>>4)*8 + j][c*16 + (l&15)]
// Coalesced via an LDS transpose of each 32x64 tile.  (proven R2-R7)
// ---------------------------------------------------------------------------
__global__ __launch_bounds__(256) void prep_x(const float* __restrict__ x,
                                              _Float16* __restrict__ ws) {
    __shared__ float sx[32][65];
    const int tid = threadIdx.x;
    const int t   = blockIdx.x;    // 0..511 ; x rows 32t..32t+31 (= K dim)
    {
        int r  = tid >> 3;
        int c8 = (tid & 7) * 8;
        const float* src = x + ((size_t)t * 32 + r) * DD + c8;
        f32x4 a = *(const f32x4*)src;
        f32x4 b = *(const f32x4*)(src + 4);
#pragma unroll
        for (int j = 0; j < 4; ++j) { sx[r][c8 + j] = a[j]; sx[r][c8 + 4 + j] = b[j]; }
    }
    __syncthreads();
    const int l = tid & 63;
    const int c = tid >> 6;
    const int q = l >> 4;
    const int m = l & 15;
    f16x8 v;
#pragma unroll
    for (int j = 0; j < 8; ++j)
        v[j] = (_Float16)sx[q * 8 + j][c * 16 + m];
    *(f16x8*)(ws + (((size_t)t * 256 + c * 64 + l) * 8)) = v;
}

// ---------------------------------------------------------------------------
// Bit-GEMM (R3's proven skeleton: LDS-staged B on lgkmcnt, one barrier per
// K=128 chunk; adj side now 32 MiB of pk bits, not 1 GiB of ints).
// A-side: lane (q,m) loads its row's 16 pk dwords per K=512 block as two
// i32x4 (a0 = dwords 0-3 = i=0, a1 = dwords 8-11.. wait: a0 = [np*8, +4),
// a1 = [np*8+4, +8) with np = K256-pair index).  Chunk n (K=128): h = n&1,
// block pair np = n>>1:  D_e for e=0..3 = { a0[h], a0[2+h], a1[h], a1[2+h] }
// (static indices via explicit h=0/h=1 bodies).  Frag bit for (s,q,j):
//   ai[j] = bit (8s + 2q + (j>>2)) of D[j&3]     [derived from pack layout:
//   c' = 32*s_loc+8q+j -> e=j&3, b=8*(s_loc&3)+2q+(j>>2), h=(s_loc>>2)&1,
//   i=s_loc>>3, with s_loc = (n&3)*4+s].
// Epilogue: out = acc + x directly (no K-split, no partials).
// ---------------------------------------------------------------------------
__global__ __launch_bounds__(256) void graphpool_gemm(const u32* __restrict__ pk,
                                                      const float* __restrict__ x,
                                                      const _Float16* __restrict__ xs,
                                                      float* __restrict__ out) {
    __shared__ _Float16 sB[2][8192];   // 2 x 16 KiB

    const int tid = threadIdx.x;
    const int w   = tid >> 6;
    const int l   = tid & 63;
    const int q   = l >> 4;
    const int m   = l & 15;
    const int row16 = blockIdx.x * 64 + w * 16;

    // pk row base: row stride = 16384/32 = 512 dwords
    const i32x4* aptr = (const i32x4*)(pk + (size_t)(row16 + m) * 512);

    f32x4 acc[4];
#pragma unroll
    for (int c = 0; c < 4; ++c) acc[c] = (f32x4){0.f, 0.f, 0.f, 0.f};

    i32x4 av[2][2];    // [buf][vec] : K=256 pair of bit-vectors
    f16x8 sreg[4];     // B staging regs

    auto loadA = [&](int np, int buf) {
        av[buf][0] = aptr[np * 2];
        av[buf][1] = aptr[np * 2 + 1];
    };
    auto stageRead = [&](int n) {
        const f16x8* src = (const f16x8*)xs + (size_t)n * 1024;
#pragma unroll
        for (int p = 0; p < 4; ++p) sreg[p] = src[p * 256 + tid];
    };
    auto stageWrite = [&](int buf) {
        f16x8* dst = (f16x8*)sB[buf];
#pragma unroll
        for (int p = 0; p < 4; ++p) dst[p * 256 + tid] = sreg[p];
    };

    auto doChunk = [&](int n, u32 D0, u32 D1, u32 D2, u32 D3) {
        const int buf = n & 1;
        const bool pf = (n + 1 < 128);
        if (pf) stageRead(n + 1);
#pragma unroll
        for (int s = 0; s < 4; ++s) {
            const u32 bb = 8 * s + 2 * q;
            s16x8 ai;
            ai[0] = ((D0 >> bb) & 1u)       ? (short)0x3C00 : (short)0;
            ai[1] = ((D1 >> bb) & 1u)       ? (short)0x3C00 : (short)0;
            ai[2] = ((D2 >> bb) & 1u)       ? (short)0x3C00 : (short)0;
            ai[3] = ((D3 >> bb) & 1u)       ? (short)0x3C00 : (short)0;
            ai[4] = ((D0 >> (bb + 1)) & 1u) ? (short)0x3C00 : (short)0;
            ai[5] = ((D1 >> (bb + 1)) & 1u) ? (short)0x3C00 : (short)0;
            ai[6] = ((D2 >> (bb + 1)) & 1u) ? (short)0x3C00 : (short)0;
            ai[7] = ((D3 >> (bb + 1)) & 1u) ? (short)0x3C00 : (short)0;
            f16x8 af = __builtin_bit_cast(f16x8, ai);
#pragma unroll
            for (int c = 0; c < 4; ++c) {
                f16x8 bf = *(const f16x8*)&sB[buf][((s * 4 + c) * 64 + l) * 8];
                acc[c] = __builtin_amdgcn_mfma_f32_16x16x32_f16(af, bf, acc[c], 0, 0, 0);
            }
        }
        if (pf) stageWrite(buf ^ 1);
        __syncthreads();
    };

    // prologue: chunk 0's B into buf 0, A pair 0 into av[0]
    stageRead(0);
    loadA(0, 0);
    stageWrite(0);
    __syncthreads();

    for (int np = 0; np < 64; ++np) {
        const int ab = np & 1;
        if (np + 1 < 64) loadA(np + 1, ab ^ 1);
        const i32x4 a0 = av[ab][0], a1 = av[ab][1];
        // chunk 2np   (h=0): e-dwords = a0.x, a0.z, a1.x, a1.z
        doChunk(2 * np,     (u32)a0.x, (u32)a0.z, (u32)a1.x, (u32)a1.z);
        // chunk 2np+1 (h=1): e-dwords = a0.y, a0.w, a1.y, a1.w
        doChunk(2 * np + 1, (u32)a0.y, (u32)a0.w, (u32)a1.y, (u32)a1.w);
    }

    // epilogue: C layout col = c*16+m, row = q*4+r ; add self term +x
#pragma unroll
    for (int c = 0; c < 4; ++c) {
#pragma unroll
        for (int r = 0; r < 4; ++r) {
            int row = row16 + q * 4 + r;
            int col = c * 16 + m;
            size_t off = (size_t)row * DD + col;
            out[off] = acc[c][r] + x[off];
        }
    }
}

// ---------------------------------------------------------------------------
// Safety-net fallback if ws is too small (needs 2 MiB xs + 32 MiB pk).
// ---------------------------------------------------------------------------
__global__ void graphpool_fallback(const int* __restrict__ adj,
                                   const float* __restrict__ x,
                                   float* __restrict__ out) {
    int i = blockIdx.x;
    int d = threadIdx.x;   // 64 threads
    float acc = x[(size_t)i * DD + d];
    const int* row = adj + (size_t)i * NN;
    for (int j = 0; j < NN; ++j)
        if (row[j]) acc += x[(size_t)j * DD + d];
    out[(size_t)i * DD + d] = acc;
}

extern "C" void kernel_launch(void* const* d_in, const int* in_sizes, int n_in,
                              void* d_out, int out_size, void* d_ws, size_t ws_size,
                              hipStream_t stream) {
    const float* x   = (const float*)d_in[0];
    const int*   adj = (const int*)d_in[1];
    float*       out = (float*)d_out;

    const size_t xs_bytes = (size_t)NN * DD * sizeof(_Float16);      // 2 MiB
    const size_t pk_bytes = (size_t)NN * (NN / 32) * sizeof(u32);    // 32 MiB
    if (ws_size >= xs_bytes + pk_bytes) {
        _Float16* xs = (_Float16*)d_ws;
        u32*      pk = (u32*)((char*)d_ws + xs_bytes);
        pack_adj<<<1024, 256, 0, stream>>>(adj, pk);
        prep_x<<<512, 256, 0, stream>>>(x, xs);
        graphpool_gemm<<<256, 256, 0, stream>>>(pk, x, xs, out);
    } else {
        graphpool_fallback<<<NN, 64, 0, stream>>>(adj, x, out);
    }
}

// Round 9
// 1548.317 us; speedup vs baseline: 10.3105x; 1.0133x over previous
//
#include <hip/hip_runtime.h>

#define NN 16384   // n_nodes
#define DD 64      // feature dim

typedef _Float16 f16x8 __attribute__((ext_vector_type(8)));
typedef short    s16x8 __attribute__((ext_vector_type(8)));
typedef float    f32x4 __attribute__((ext_vector_type(4)));
typedef int      i32x4 __attribute__((ext_vector_type(4)));
typedef unsigned u32;
typedef unsigned long long u64;

// ---------------------------------------------------------------------------
// pack_adj v2: bit-pack adj (1 GiB of 0/1 int32) -> pk (32 MiB).
// R8's version put its double-buffer in SCRATCH (runtime-indexed array,
// rule #20; VGPR_Count=16 proved it) -> 29 GB/s.  v2: NAMED registers only,
// manual 2-stage pipeline, no arrays.  16384 waves (4096 blocks), each owns
// a contiguous 64 KiB slice read as lane-contiguous dwordx4 pairs
// (instr i, lane l -> ints [seg*512 + i*256 + 4l, +4)) -- the m13 pattern.
// Packing (identical to R8, gemm-compatible): 8 ballots + cndmask tree;
// lane n<16 stores pk[seg*16+n]; pk dword d=i*8+e*2+h, bit b=(c'>>2)&31
// <-> col i*256 + h*128 + 4b + e of the segment.
// ---------------------------------------------------------------------------
__global__ __launch_bounds__(256) void pack_adj(const int* __restrict__ adj,
                                                u32* __restrict__ pk) {
    const int tid = threadIdx.x;
    const int w   = tid >> 6;
    const int l   = tid & 63;
    const int g   = blockIdx.x * 4 + w;    // global wave 0..16383

    const i32x4* p = (const i32x4*)(adj + (size_t)g * 16384) + l;

    i32x4 cur0 = p[0];
    i32x4 cur1 = p[64];

    for (int it = 0; it < 32; ++it) {
        i32x4 nxt0, nxt1;
        if (it + 1 < 32) {
            nxt0 = p[(it + 1) * 128];
            nxt1 = p[(it + 1) * 128 + 64];
        }

        const u64 b00 = __ballot(cur0.x != 0);   // i=0,e=0
        const u64 b01 = __ballot(cur0.y != 0);
        const u64 b02 = __ballot(cur0.z != 0);
        const u64 b03 = __ballot(cur0.w != 0);
        const u64 b10 = __ballot(cur1.x != 0);   // i=1
        const u64 b11 = __ballot(cur1.y != 0);
        const u64 b12 = __ballot(cur1.z != 0);
        const u64 b13 = __ballot(cur1.w != 0);

        auto half = [&](u64 b) { return (l & 1) ? (u32)(b >> 32) : (u32)b; };
        const u32 e0 = half(b00), e1 = half(b01), e2 = half(b02), e3 = half(b03);
        const u32 f0 = half(b10), f1 = half(b11), f2 = half(b12), f3 = half(b13);
        const u32 x01 = ((l >> 1) & 1) ? e1 : e0;
        const u32 x23 = ((l >> 1) & 1) ? e3 : e2;
        const u32 xe  = ((l >> 2) & 1) ? x23 : x01;
        const u32 y01 = ((l >> 1) & 1) ? f1 : f0;
        const u32 y23 = ((l >> 1) & 1) ? f3 : f2;
        const u32 yf  = ((l >> 2) & 1) ? y23 : y01;
        const u32 val = ((l >> 3) & 1) ? yf : xe;

        if (l < 16) {
            const size_t seg = (size_t)g * 32 + it;
            pk[seg * 16 + l] = val;
        }

        cur0 = nxt0;
        cur1 = nxt1;
    }
}

// ---------------------------------------------------------------------------
// prep_x: convert x (fp32 [NN][64]) into f16 in exact MFMA B-fragment order:
//   xs[((T*4 + c)*64 + l)*8 + j] = x[32*T + (l>>4)*8 + j][c*16 + (l&15)]
// Coalesced via an LDS transpose of each 32x64 tile.  (proven R2-R8)
// ---------------------------------------------------------------------------
__global__ __launch_bounds__(256) void prep_x(const float* __restrict__ x,
                                              _Float16* __restrict__ ws) {
    __shared__ float sx[32][65];
    const int tid = threadIdx.x;
    const int t   = blockIdx.x;    // 0..511 ; x rows 32t..32t+31 (= K dim)
    {
        int r  = tid >> 3;
        int c8 = (tid & 7) * 8;
        const float* src = x + ((size_t)t * 32 + r) * DD + c8;
        f32x4 a = *(const f32x4*)src;
        f32x4 b = *(const f32x4*)(src + 4);
#pragma unroll
        for (int j = 0; j < 4; ++j) { sx[r][c8 + j] = a[j]; sx[r][c8 + 4 + j] = b[j]; }
    }
    __syncthreads();
    const int l = tid & 63;
    const int c = tid >> 6;
    const int q = l >> 4;
    const int m = l & 15;
    f16x8 v;
#pragma unroll
    for (int j = 0; j < 8; ++j)
        v[j] = (_Float16)sx[q * 8 + j][c * 16 + m];
    *(f16x8*)(ws + (((size_t)t * 256 + c * 64 + l) * 8)) = v;
}

// ---------------------------------------------------------------------------
// Bit-GEMM (unchanged from R8, correctness-proven; reads 32 MiB pk + L2-hot
// xs; LDS-staged B on lgkmcnt, one barrier per K=128 chunk).
// A-side: lane (q,m) loads its row's pk dwords as i32x4 pairs per K=512.
// Chunk n: h=n&1, np=n>>1; e-dwords = {a0[h],a0[2+h],a1[h],a1[2+h]} (static
// h bodies).  Frag bit for (s,q,j): ai[j] = bit (8s+2q+(j>>2)) of D[j&3].
// Epilogue: out = acc + x directly.
// ---------------------------------------------------------------------------
__global__ __launch_bounds__(256) void graphpool_gemm(const u32* __restrict__ pk,
                                                      const float* __restrict__ x,
                                                      const _Float16* __restrict__ xs,
                                                      float* __restrict__ out) {
    __shared__ _Float16 sB[2][8192];   // 2 x 16 KiB

    const int tid = threadIdx.x;
    const int w   = tid >> 6;
    const int l   = tid & 63;
    const int q   = l >> 4;
    const int m   = l & 15;
    const int row16 = blockIdx.x * 64 + w * 16;

    // pk row base: row stride = 16384/32 = 512 dwords
    const i32x4* aptr = (const i32x4*)(pk + (size_t)(row16 + m) * 512);

    f32x4 acc[4];
#pragma unroll
    for (int c = 0; c < 4; ++c) acc[c] = (f32x4){0.f, 0.f, 0.f, 0.f};

    i32x4 av[2][2];    // [buf][vec] : K=256 pair of bit-vectors
    f16x8 sreg[4];     // B staging regs

    auto loadA = [&](int np, int buf) {
        av[buf][0] = aptr[np * 2];
        av[buf][1] = aptr[np * 2 + 1];
    };
    auto stageRead = [&](int n) {
        const f16x8* src = (const f16x8*)xs + (size_t)n * 1024;
#pragma unroll
        for (int p = 0; p < 4; ++p) sreg[p] = src[p * 256 + tid];
    };
    auto stageWrite = [&](int buf) {
        f16x8* dst = (f16x8*)sB[buf];
#pragma unroll
        for (int p = 0; p < 4; ++p) dst[p * 256 + tid] = sreg[p];
    };

    auto doChunk = [&](int n, u32 D0, u32 D1, u32 D2, u32 D3) {
        const int buf = n & 1;
        const bool pf = (n + 1 < 128);
        if (pf) stageRead(n + 1);
#pragma unroll
        for (int s = 0; s < 4; ++s) {
            const u32 bb = 8 * s + 2 * q;
            s16x8 ai;
            ai[0] = ((D0 >> bb) & 1u)       ? (short)0x3C00 : (short)0;
            ai[1] = ((D1 >> bb) & 1u)       ? (short)0x3C00 : (short)0;
            ai[2] = ((D2 >> bb) & 1u)       ? (short)0x3C00 : (short)0;
            ai[3] = ((D3 >> bb) & 1u)       ? (short)0x3C00 : (short)0;
            ai[4] = ((D0 >> (bb + 1)) & 1u) ? (short)0x3C00 : (short)0;
            ai[5] = ((D1 >> (bb + 1)) & 1u) ? (short)0x3C00 : (short)0;
            ai[6] = ((D2 >> (bb + 1)) & 1u) ? (short)0x3C00 : (short)0;
            ai[7] = ((D3 >> (bb + 1)) & 1u) ? (short)0x3C00 : (short)0;
            f16x8 af = __builtin_bit_cast(f16x8, ai);
#pragma unroll
            for (int c = 0; c < 4; ++c) {
                f16x8 bf = *(const f16x8*)&sB[buf][((s * 4 + c) * 64 + l) * 8];
                acc[c] = __builtin_amdgcn_mfma_f32_16x16x32_f16(af, bf, acc[c], 0, 0, 0);
            }
        }
        if (pf) stageWrite(buf ^ 1);
        __syncthreads();
    };

    // prologue: chunk 0's B into buf 0, A pair 0 into av[0]
    stageRead(0);
    loadA(0, 0);
    stageWrite(0);
    __syncthreads();

    for (int np = 0; np < 64; ++np) {
        const int ab = np & 1;
        if (np + 1 < 64) loadA(np + 1, ab ^ 1);
        const i32x4 a0 = av[ab][0], a1 = av[ab][1];
        // chunk 2np   (h=0): e-dwords = a0.x, a0.z, a1.x, a1.z
        doChunk(2 * np,     (u32)a0.x, (u32)a0.z, (u32)a1.x, (u32)a1.z);
        // chunk 2np+1 (h=1): e-dwords = a0.y, a0.w, a1.y, a1.w
        doChunk(2 * np + 1, (u32)a0.y, (u32)a0.w, (u32)a1.y, (u32)a1.w);
    }

    // epilogue: C layout col = c*16+m, row = q*4+r ; add self term +x
#pragma unroll
    for (int c = 0; c < 4; ++c) {
#pragma unroll
        for (int r = 0; r < 4; ++r) {
            int row = row16 + q * 4 + r;
            int col = c * 16 + m;
            size_t off = (size_t)row * DD + col;
            out[off] = acc[c][r] + x[off];
        }
    }
}

// ---------------------------------------------------------------------------
// Safety-net fallback if ws is too small (needs 2 MiB xs + 32 MiB pk).
// ---------------------------------------------------------------------------
__global__ void graphpool_fallback(const int* __restrict__ adj,
                                   const float* __restrict__ x,
                                   float* __restrict__ out) {
    int i = blockIdx.x;
    int d = threadIdx.x;   // 64 threads
    float acc = x[(size_t)i * DD + d];
    const int* row = adj + (size_t)i * NN;
    for (int j = 0; j < NN; ++j)
        if (row[j]) acc += x[(size_t)j * DD + d];
    out[(size_t)i * DD + d] = acc;
}

extern "C" void kernel_launch(void* const* d_in, const int* in_sizes, int n_in,
                              void* d_out, int out_size, void* d_ws, size_t ws_size,
                              hipStream_t stream) {
    const float* x   = (const float*)d_in[0];
    const int*   adj = (const int*)d_in[1];
    float*       out = (float*)d_out;

    const size_t xs_bytes = (size_t)NN * DD * sizeof(_Float16);      // 2 MiB
    const size_t pk_bytes = (size_t)NN * (NN / 32) * sizeof(u32);    // 32 MiB
    if (ws_size >= xs_bytes + pk_bytes) {
        _Float16* xs = (_Float16*)d_ws;
        u32*      pk = (u32*)((char*)d_ws + xs_bytes);
        pack_adj<<<4096, 256, 0, stream>>>(adj, pk);
        prep_x<<<512, 256, 0, stream>>>(x, xs);
        graphpool_gemm<<<256, 256, 0, stream>>>(pk, x, xs, out);
    } else {
        graphpool_fallback<<<NN, 64, 0, stream>>>(adj, x, out);
    }
}

// Round 10
// 1371.456 us; speedup vs baseline: 11.6401x; 1.1290x over previous
//
#include <hip/hip_runtime.h>

#define NN 16384   // n_nodes
#define DD 64      // feature dim
#define SPLIT 32             // K-splits per row-block
#define KQ (NN / SPLIT)      // 512 K per block
#define NCH (KQ / 128)       // 4 chunks of K=128 per block
#define NPAIR (KQ / 256)     // 2 pairs of K=256 per block

typedef _Float16 f16x8 __attribute__((ext_vector_type(8)));
typedef short    s16x8 __attribute__((ext_vector_type(8)));
typedef float    f32x4 __attribute__((ext_vector_type(4)));
typedef int      i32x4 __attribute__((ext_vector_type(4)));
typedef unsigned u32;
typedef unsigned long long u64;

// ---------------------------------------------------------------------------
// prep_x: convert x (fp32 [NN][64]) into f16 in exact MFMA B-fragment order:
//   xs[((T*4 + c)*64 + l)*8 + j] = x[32*T + (l>>4)*8 + j][c*16 + (l&15)]
// Coalesced via an LDS transpose of each 32x64 tile.  (proven R2-R9)
// ---------------------------------------------------------------------------
__global__ __launch_bounds__(256) void prep_x(const float* __restrict__ x,
                                              _Float16* __restrict__ ws) {
    __shared__ float sx[32][65];
    const int tid = threadIdx.x;
    const int t   = blockIdx.x;    // 0..511 ; x rows 32t..32t+31 (= K dim)
    {
        int r  = tid >> 3;
        int c8 = (tid & 7) * 8;
        const float* src = x + ((size_t)t * 32 + r) * DD + c8;
        f32x4 a = *(const f32x4*)src;
        f32x4 b = *(const f32x4*)(src + 4);
#pragma unroll
        for (int j = 0; j < 4; ++j) { sx[r][c8 + j] = a[j]; sx[r][c8 + 4 + j] = b[j]; }
    }
    __syncthreads();
    const int l = tid & 63;
    const int c = tid >> 6;
    const int q = l >> 4;
    const int m = l & 15;
    f16x8 v;
#pragma unroll
    for (int j = 0; j < 8; ++j)
        v[j] = (_Float16)sx[q * 8 + j][c * 16 + m];
    *(f16x8*)(ws + (((size_t)t * 256 + c * 64 + l) * 8)) = v;
}

// ---------------------------------------------------------------------------
// Fused zero-barrier GEMM, R6 structure + m13-width adj loads (i32x4/lane,
// 1 KiB per burst).  Block (rb,kq): rows rb*64..+63, K in [kq*512, +512).
// B panel (64 KiB) LDS-resident behind ONE barrier; K-loop barrier-free.
// Per K=256 pair: 16 rows x one i32x4 load (lane l -> cols 4l..4l+3);
// 4 u64 ballots/row (bit b of ballot_e <-> col 4b+e; lo/hi half = h);
// lane e*16+m owns row m's (e, h) bit-dwords -> ds_bpermute exchange;
// decode ai[j] = bit(8s+2q+(j>>2)) of D[j&3]  (R8/R9-proven mapping).
// Single areg buffer (64 VGPR), named mine regs: pair p+1's loads are in
// flight during pair p's 2 chunks of MFMA.
// ---------------------------------------------------------------------------
__global__ __launch_bounds__(256, 2) void graphpool_gemm(const int* __restrict__ adj,
                                                         const _Float16* __restrict__ xs,
                                                         float* __restrict__ part) {
    __shared__ _Float16 sB[NCH][8192];   // 4 x 16 KiB = 64 KiB

    const int tid = threadIdx.x;
    const int w   = tid >> 6;
    const int l   = tid & 63;
    const int q   = l >> 4;
    const int m   = l & 15;

    const int rb    = blockIdx.x >> 5;   // row-block 0..255
    const int kq    = blockIdx.x & 31;   // K-split  0..31
    const int row16 = rb * 64 + w * 16;

    // stage entire B panel (L2-resident xs), then the ONLY barrier
#pragma unroll
    for (int n = 0; n < NCH; ++n) {
        const f16x8* src = (const f16x8*)xs + ((size_t)(kq * NCH + n)) * 1024;
        f16x8 t0 = src[tid], t1 = src[256 + tid], t2 = src[512 + tid], t3 = src[768 + tid];
        f16x8* dst = (f16x8*)sB[n];
        dst[tid] = t0; dst[256 + tid] = t1; dst[512 + tid] = t2; dst[768 + tid] = t3;
    }
    __syncthreads();

    // adj loads all issued AFTER the barrier: never drained again
    const int* abase = adj + (size_t)row16 * NN + (size_t)kq * KQ;

    f32x4 acc[4];
#pragma unroll
    for (int c = 0; c < 4; ++c) acc[c] = (f32x4){0.f, 0.f, 0.f, 0.f};

    i32x4 areg[16];   // single pair buffer; all indices compile-time (unrolled)

    auto loadPair = [&](int p) {
#pragma unroll
        for (int rr = 0; rr < 16; ++rr)
            areg[rr] = ((const i32x4*)(abase + (size_t)rr * NN + p * 256))[l];
    };

    u32 m0, m1;   // lane (e*16+m) ends owning row m's dwords (e,h=0) / (e,h=1)
    auto packPair = [&]() {
        u32 r0 = 0, r1 = 0;
        const bool selE1 = ((l >> 4) & 1) != 0;
        const bool selE2 = ((l >> 4) & 2) != 0;
#pragma unroll
        for (int rr = 0; rr < 16; ++rr) {
            const i32x4 v = areg[rr];
            const u64 b0 = __ballot(v.x != 0);   // e=0: bit b <-> col 4b+0
            const u64 b1 = __ballot(v.y != 0);
            const u64 b2 = __ballot(v.z != 0);
            const u64 b3 = __ballot(v.w != 0);
            const u32 loA = selE1 ? (u32)b1 : (u32)b0;
            const u32 loB = selE1 ? (u32)b3 : (u32)b2;
            const u32 loS = selE2 ? loB : loA;          // h=0 dword for e=l>>4
            const u32 hiA = selE1 ? (u32)(b1 >> 32) : (u32)(b0 >> 32);
            const u32 hiB = selE1 ? (u32)(b3 >> 32) : (u32)(b2 >> 32);
            const u32 hiS = selE2 ? hiB : hiA;          // h=1 dword
            const bool own = ((l & 15) == rr);
            r0 = own ? loS : r0;
            r1 = own ? hiS : r1;
        }
        m0 = r0; m1 = r1;
    };

    // chunk ci (K=128, B slab sB[ci]); D_e = row m's bit-dword (e, h)
    auto doChunk = [&](int ci, u32 D0, u32 D1, u32 D2, u32 D3) {
#pragma unroll
        for (int s = 0; s < 4; ++s) {
            const u32 bb = 8 * s + 2 * q;
            s16x8 ai;
            ai[0] = ((D0 >> bb) & 1u)       ? (short)0x3C00 : (short)0;
            ai[1] = ((D1 >> bb) & 1u)       ? (short)0x3C00 : (short)0;
            ai[2] = ((D2 >> bb) & 1u)       ? (short)0x3C00 : (short)0;
            ai[3] = ((D3 >> bb) & 1u)       ? (short)0x3C00 : (short)0;
            ai[4] = ((D0 >> (bb + 1)) & 1u) ? (short)0x3C00 : (short)0;
            ai[5] = ((D1 >> (bb + 1)) & 1u) ? (short)0x3C00 : (short)0;
            ai[6] = ((D2 >> (bb + 1)) & 1u) ? (short)0x3C00 : (short)0;
            ai[7] = ((D3 >> (bb + 1)) & 1u) ? (short)0x3C00 : (short)0;
            f16x8 af = __builtin_bit_cast(f16x8, ai);
#pragma unroll
            for (int c = 0; c < 4; ++c) {
                f16x8 bf = *(const f16x8*)&sB[ci][((s * 4 + c) * 64 + l) * 8];
                acc[c] = __builtin_amdgcn_mfma_f32_16x16x32_f16(af, bf, acc[c], 0, 0, 0);
            }
        }
    };

    auto exchDo = [&](int pairBase, u32 mh0, u32 mh1) {
        int rA0, rA1, rA2, rA3;
#pragma unroll
        for (int e = 0; e < 4; ++e) {
            int v = __builtin_amdgcn_ds_bpermute(((e << 4) | m) << 2, (int)mh0);
            if (e == 0) rA0 = v; else if (e == 1) rA1 = v;
            else if (e == 2) rA2 = v; else rA3 = v;
        }
        doChunk(pairBase, (u32)rA0, (u32)rA1, (u32)rA2, (u32)rA3);
#pragma unroll
        for (int e = 0; e < 4; ++e) {
            int v = __builtin_amdgcn_ds_bpermute(((e << 4) | m) << 2, (int)mh1);
            if (e == 0) rA0 = v; else if (e == 1) rA1 = v;
            else if (e == 2) rA2 = v; else rA3 = v;
        }
        doChunk(pairBase + 1, (u32)rA0, (u32)rA1, (u32)rA2, (u32)rA3);
    };

    // pair 0: load, pack (stall covered by other waves), prefetch pair 1
    loadPair(0);
    packPair();                 // consumes areg -> buffer free
    u32 p0m0 = m0, p0m1 = m1;
    loadPair(1);                // in flight during pair-0 compute
    exchDo(0, p0m0, p0m1);      // chunks 0,1

    packPair();                 // pair-1 bits (loads arrived under MFMA)
    exchDo(2, m0, m1);          // chunks 2,3

    // partial C write: col = c*16+m, row = q*4+r  (128 MiB total -> L3)
    float* po = part + (size_t)kq * NN * DD;
#pragma unroll
    for (int c = 0; c < 4; ++c) {
#pragma unroll
        for (int r = 0; r < 4; ++r) {
            size_t off = (size_t)(row16 + q * 4 + r) * DD + c * 16 + m;
            po[off] = acc[c][r];
        }
    }
}

// ---------------------------------------------------------------------------
// Final reduce: out = sum(part[0..31]) + x (self term).  ~132 MiB, L3-hot.
// ---------------------------------------------------------------------------
__global__ __launch_bounds__(256) void reduce_add(const float* __restrict__ part,
                                                  const float* __restrict__ x,
                                                  float* __restrict__ out) {
    size_t i = (size_t)blockIdx.x * 256 + threadIdx.x;   // f32x4 index, 262144 total
    f32x4 v = ((const f32x4*)x)[i];
#pragma unroll
    for (int g = 0; g < SPLIT; ++g)
        v += ((const f32x4*)(part + (size_t)g * NN * DD))[i];
    ((f32x4*)out)[i] = v;
}

// ---------------------------------------------------------------------------
// Safety-net fallback if ws is too small (needs 2 MiB xs + 128 MiB partials).
// ---------------------------------------------------------------------------
__global__ void graphpool_fallback(const int* __restrict__ adj,
                                   const float* __restrict__ x,
                                   float* __restrict__ out) {
    int i = blockIdx.x;
    int d = threadIdx.x;   // 64 threads
    float acc = x[(size_t)i * DD + d];
    const int* row = adj + (size_t)i * NN;
    for (int j = 0; j < NN; ++j)
        if (row[j]) acc += x[(size_t)j * DD + d];
    out[(size_t)i * DD + d] = acc;
}

extern "C" void kernel_launch(void* const* d_in, const int* in_sizes, int n_in,
                              void* d_out, int out_size, void* d_ws, size_t ws_size,
                              hipStream_t stream) {
    const float* x   = (const float*)d_in[0];
    const int*   adj = (const int*)d_in[1];
    float*       out = (float*)d_out;

    const size_t xs_bytes   = (size_t)NN * DD * sizeof(_Float16);        // 2 MiB
    const size_t part_bytes = (size_t)SPLIT * NN * DD * sizeof(float);   // 128 MiB
    if (ws_size >= xs_bytes + part_bytes) {
        _Float16* xs   = (_Float16*)d_ws;
        float*    part = (float*)((char*)d_ws + xs_bytes);
        prep_x<<<512, 256, 0, stream>>>(x, xs);
        graphpool_gemm<<<256 * SPLIT, 256, 0, stream>>>(adj, xs, part);
        reduce_add<<<1024, 256, 0, stream>>>(part, x, out);
    } else {
        graphpool_fallback<<<NN, 64, 0, stream>>>(adj, x, out);
    }
}